// Round 1
// baseline (59.430 us; speedup 1.0000x reference)
//
#include <hip/hip_runtime.h>
#include <math.h>

#define BB 2
#define NN 512
#define NIN 64
#define NF 192
#define HH 128
#define NOUT 8

__device__ __forceinline__ float celu1(float x) {
    return x > 0.0f ? x : expm1f(x);
}

// ---------------------------------------------------------------------------
// Kernel A: context pairing + fc_l/fc_r + CELU  ->  hl, hr  [B,N,H] f32
// grid: B*N/NP blocks, 128 threads. NP=2 positions per block.
// ---------------------------------------------------------------------------
__global__ __launch_bounds__(128) void h_kernel(
    const float* __restrict__ x_l, const float* __restrict__ x_r,
    const float* __restrict__ Wl, const float* __restrict__ bl,
    const float* __restrict__ Wr, const float* __restrict__ br,
    float* __restrict__ hl, float* __restrict__ hr)
{
    const int NP = 2;
    int blk = blockIdx.x;             // 0 .. B*N/NP-1
    int b   = blk / (NN / NP);
    int i0  = (blk % (NN / NP)) * NP;
    int tid = threadIdx.x;

    __shared__ __align__(16) float zl[NP][NF];
    __shared__ __align__(16) float zr[NP][NF];

    for (int idx = tid; idx < NP * NF; idx += 128) {
        int p = idx / NF;
        int f = idx % NF;
        int part = f >> 6;
        int c = f & 63;
        int i = i0 + p;
        float vl, vr;
        if (part == 0) {
            // NB: faithful bug — z_r list also starts with x_l
            float v = x_l[(b * NN + i) * NIN + c];
            vl = v; vr = v;
        } else if (part == 1) {
            vl = (i >= 1)     ? x_l[(b * NN + i - 1) * NIN + c] : 0.0f;  // shift_fwd(x_l)
            vr = (i + 1 < NN) ? x_r[(b * NN + i + 1) * NIN + c] : 0.0f;  // shift_bwd(x_r)
        } else {
            vl = (i + 1 < NN) ? x_l[(b * NN + i + 1) * NIN + c] : 0.0f;  // shift_bwd(x_l)
            vr = (i >= 1)     ? x_r[(b * NN + i - 1) * NIN + c] : 0.0f;  // shift_fwd(x_r)
        }
        zl[p][f] = vl;
        zr[p][f] = vr;
    }
    __syncthreads();

    int h = tid;
    float accl[NP], accr[NP];
    #pragma unroll
    for (int p = 0; p < NP; ++p) { accl[p] = bl[h]; accr[p] = br[h]; }

    const float4* wl4 = (const float4*)(Wl + h * NF);
    const float4* wr4 = (const float4*)(Wr + h * NF);
    #pragma unroll 4
    for (int f4 = 0; f4 < NF / 4; ++f4) {
        float4 wl = wl4[f4];
        float4 wr = wr4[f4];
        #pragma unroll
        for (int p = 0; p < NP; ++p) {
            float4 a = *(const float4*)&zl[p][f4 * 4];
            float4 c = *(const float4*)&zr[p][f4 * 4];
            accl[p] += a.x * wl.x + a.y * wl.y + a.z * wl.z + a.w * wl.w;
            accr[p] += c.x * wr.x + c.y * wr.y + c.z * wr.z + c.w * wr.w;
        }
    }
    #pragma unroll
    for (int p = 0; p < NP; ++p) {
        hl[(b * NN + i0 + p) * HH + h] = celu1(accl[p]);
        hr[(b * NN + i0 + p) * HH + h] = celu1(accr[p]);
    }
}

// ---------------------------------------------------------------------------
// Kernel B: t[b,i,o,g] = sum_h hl[b,i,h] * W[o,h,g]
// grid: dim3(2, N/8, B), 256 threads. Each block: 8 positions, 64 g, all o.
// thread -> (o2 = tid>>6 in 0..3 covering o = o2*2 + {0,1}; g = gh*64 + tid&63)
// ---------------------------------------------------------------------------
__global__ __launch_bounds__(256) void t_kernel(
    const float* __restrict__ hl, const float* __restrict__ W,
    float* __restrict__ t)
{
    const int PI = 8;
    int gh = blockIdx.x;              // g half: 0/1
    int i0 = blockIdx.y * PI;
    int b  = blockIdx.z;
    int tid = threadIdx.x;
    int o2 = tid >> 6;                // 0..3
    int g  = gh * 64 + (tid & 63);

    __shared__ float hl_s[PI][HH];
    for (int idx = tid; idx < PI * HH; idx += 256) {
        int p = idx >> 7, hh2 = idx & 127;
        hl_s[p][hh2] = hl[(b * NN + i0 + p) * HH + hh2];
    }
    __syncthreads();

    float acc[PI][2];
    #pragma unroll
    for (int p = 0; p < PI; ++p) { acc[p][0] = 0.f; acc[p][1] = 0.f; }

    int o_0 = o2 * 2;
    const float* W0 = W + (o_0    ) * HH * HH + g;
    const float* W1 = W + (o_0 + 1) * HH * HH + g;
    #pragma unroll 4
    for (int h = 0; h < HH; ++h) {
        float w0 = W0[h * HH];
        float w1 = W1[h * HH];
        #pragma unroll
        for (int p = 0; p < PI; ++p) {
            float hv = hl_s[p][h];
            acc[p][0] += hv * w0;
            acc[p][1] += hv * w1;
        }
    }
    #pragma unroll
    for (int p = 0; p < PI; ++p) {
        t[((b * NN + i0 + p) * NOUT + o_0    ) * HH + g] = acc[p][0];
        t[((b * NN + i0 + p) * NOUT + o_0 + 1) * HH + g] = acc[p][1];
    }
}

// ---------------------------------------------------------------------------
// Kernel C: out[b,i,j,o] = sum_g t[b,i,o,g] * hr[b,j,g] + bias[o]
// grid: dim3(N/32, N/32, B), block dim3(16,16).
// 32x32 (i,j) tile, 2x2 micro-tile per thread, all 8 o in registers.
// LDS: t_s[i'][g][o] (padded, +4 floats per i' row), hr_s[32][GC+1].
// ---------------------------------------------------------------------------
#define GC 32
#define TSP (GC * 8 + 4)   // padded i' row stride in floats

__global__ __launch_bounds__(256) void out_kernel(
    const float* __restrict__ t, const float* __restrict__ hr,
    const float* __restrict__ bias, float* __restrict__ out)
{
    int j0 = blockIdx.x * 32;
    int i0 = blockIdx.y * 32;
    int b  = blockIdx.z;
    int tx = threadIdx.x;   // 0..15 (j)
    int ty = threadIdx.y;   // 0..15 (i)
    int tid = ty * 16 + tx;

    __shared__ __align__(16) float t_s[32 * TSP];
    __shared__ __align__(16) float hr_s[32][GC + 1];

    float acc[8][2][2];
    #pragma unroll
    for (int o = 0; o < 8; ++o)
        #pragma unroll
        for (int ii = 0; ii < 2; ++ii)
            #pragma unroll
            for (int jj = 0; jj < 2; ++jj)
                acc[o][ii][jj] = 0.f;

    for (int g0 = 0; g0 < HH; g0 += GC) {
        // stage hr tile: 32 j x GC g
        {
            int idx = tid * 4;
            int jp = idx / GC;
            int gp = idx % GC;
            float4 v = *(const float4*)&hr[(b * NN + j0 + jp) * HH + g0 + gp];
            hr_s[jp][gp + 0] = v.x;
            hr_s[jp][gp + 1] = v.y;
            hr_s[jp][gp + 2] = v.z;
            hr_s[jp][gp + 3] = v.w;
        }
        // stage t tile: one (i',o) per thread, transpose to [i'][g][o]
        {
            int ip = tid >> 3;
            int o  = tid & 7;
            const float* src = &t[((b * NN + i0 + ip) * NOUT + o) * HH + g0];
            float* dst = &t_s[ip * TSP + o];
            #pragma unroll
            for (int gg = 0; gg < GC; gg += 4) {
                float4 v = *(const float4*)&src[gg];
                dst[(gg + 0) * 8] = v.x;
                dst[(gg + 1) * 8] = v.y;
                dst[(gg + 2) * 8] = v.z;
                dst[(gg + 3) * 8] = v.w;
            }
        }
        __syncthreads();

        #pragma unroll 4
        for (int g = 0; g < GC; ++g) {
            float h0 = hr_s[tx][g];
            float h1 = hr_s[tx + 16][g];
            float ta[8], tb[8];
            *(float4*)&ta[0] = *(const float4*)&t_s[ty * TSP + g * 8];
            *(float4*)&ta[4] = *(const float4*)&t_s[ty * TSP + g * 8 + 4];
            *(float4*)&tb[0] = *(const float4*)&t_s[(ty + 16) * TSP + g * 8];
            *(float4*)&tb[4] = *(const float4*)&t_s[(ty + 16) * TSP + g * 8 + 4];
            #pragma unroll
            for (int o = 0; o < 8; ++o) {
                acc[o][0][0] += ta[o] * h0;
                acc[o][0][1] += ta[o] * h1;
                acc[o][1][0] += tb[o] * h0;
                acc[o][1][1] += tb[o] * h1;
            }
        }
        __syncthreads();
    }

    float bsv[8];
    #pragma unroll
    for (int o = 0; o < 8; ++o) bsv[o] = bias[o];

    #pragma unroll
    for (int ii = 0; ii < 2; ++ii) {
        #pragma unroll
        for (int jj = 0; jj < 2; ++jj) {
            int i = i0 + ty + ii * 16;
            int j = j0 + tx + jj * 16;
            float4 v0, v1;
            v0.x = acc[0][ii][jj] + bsv[0];
            v0.y = acc[1][ii][jj] + bsv[1];
            v0.z = acc[2][ii][jj] + bsv[2];
            v0.w = acc[3][ii][jj] + bsv[3];
            v1.x = acc[4][ii][jj] + bsv[4];
            v1.y = acc[5][ii][jj] + bsv[5];
            v1.z = acc[6][ii][jj] + bsv[6];
            v1.w = acc[7][ii][jj] + bsv[7];
            float* dst = out + (size_t)(((b * NN + i) * NN + j)) * 8;
            *(float4*)dst = v0;
            *(float4*)(dst + 4) = v1;
        }
    }
}

// ---------------------------------------------------------------------------
extern "C" void kernel_launch(void* const* d_in, const int* in_sizes, int n_in,
                              void* d_out, int out_size, void* d_ws, size_t ws_size,
                              hipStream_t stream) {
    const float* x_l  = (const float*)d_in[0];
    const float* x_r  = (const float*)d_in[1];
    const float* Wl   = (const float*)d_in[2];
    const float* bl   = (const float*)d_in[3];
    const float* Wr   = (const float*)d_in[4];
    const float* br   = (const float*)d_in[5];
    const float* Wb   = (const float*)d_in[6];
    const float* bb   = (const float*)d_in[7];
    float* out = (float*)d_out;

    float* hl = (float*)d_ws;                       // B*N*H = 131072 floats
    float* hr = hl + BB * NN * HH;                  // 131072 floats
    float* t  = hr + BB * NN * HH;                  // B*N*8*H = 1048576 floats

    h_kernel<<<BB * NN / 2, 128, 0, stream>>>(x_l, x_r, Wl, bl, Wr, br, hl, hr);
    t_kernel<<<dim3(2, NN / 8, BB), 256, 0, stream>>>(hl, Wb, t);
    out_kernel<<<dim3(NN / 32, NN / 32, BB), dim3(16, 16), 0, stream>>>(t, hr, bb, out);
}

// Round 2
// 44.234 us; speedup vs baseline: 1.3435x; 1.3435x over previous
//
#include <hip/hip_runtime.h>
#include <math.h>

#define BB 2
#define NN 512
#define NIN 64
#define NF 192
#define HH 128
#define NOUT 8

typedef short short8 __attribute__((ext_vector_type(8)));
typedef float f32x4 __attribute__((ext_vector_type(4)));

__device__ __forceinline__ float celu1(float x) {
    return x > 0.0f ? x : expm1f(x);
}

__device__ __forceinline__ ushort f2b(float f) {
    union { float f; uint u; } v; v.f = f;
    uint r = v.u + 0x7fffu + ((v.u >> 16) & 1u);   // RNE
    return (ushort)(r >> 16);
}

// ---------------------------------------------------------------------------
// Kernel A: context pairing + fc_l/fc_r + CELU -> hl_bf, hr_bf [B*N][H] bf16
// grid: B*N/4 blocks, 128 threads, 4 positions per block.
// ---------------------------------------------------------------------------
__global__ __launch_bounds__(128) void h_kernel(
    const float* __restrict__ x_l, const float* __restrict__ x_r,
    const float* __restrict__ Wl, const float* __restrict__ bl,
    const float* __restrict__ Wr, const float* __restrict__ br,
    ushort* __restrict__ hl_bf, ushort* __restrict__ hr_bf)
{
    const int NP = 4;
    int blk = blockIdx.x;
    int b   = blk / (NN / NP);
    int i0  = (blk % (NN / NP)) * NP;
    int tid = threadIdx.x;

    __shared__ __align__(16) float zl[NP][NF];
    __shared__ __align__(16) float zr[NP][NF];

    for (int idx = tid; idx < NP * NF; idx += 128) {
        int p = idx / NF;
        int f = idx % NF;
        int part = f >> 6;
        int c = f & 63;
        int i = i0 + p;
        float vl, vr;
        if (part == 0) {
            // faithful reproduction: z_r list also starts with x_l
            float v = x_l[(b * NN + i) * NIN + c];
            vl = v; vr = v;
        } else if (part == 1) {
            vl = (i >= 1)     ? x_l[(b * NN + i - 1) * NIN + c] : 0.0f;
            vr = (i + 1 < NN) ? x_r[(b * NN + i + 1) * NIN + c] : 0.0f;
        } else {
            vl = (i + 1 < NN) ? x_l[(b * NN + i + 1) * NIN + c] : 0.0f;
            vr = (i >= 1)     ? x_r[(b * NN + i - 1) * NIN + c] : 0.0f;
        }
        zl[p][f] = vl;
        zr[p][f] = vr;
    }
    __syncthreads();

    int h = tid;
    float accl[NP], accr[NP];
    #pragma unroll
    for (int p = 0; p < NP; ++p) { accl[p] = bl[h]; accr[p] = br[h]; }

    const float4* wl4 = (const float4*)(Wl + h * NF);
    const float4* wr4 = (const float4*)(Wr + h * NF);
    #pragma unroll 4
    for (int f4 = 0; f4 < NF / 4; ++f4) {
        float4 wl = wl4[f4];
        float4 wr = wr4[f4];
        #pragma unroll
        for (int p = 0; p < NP; ++p) {
            float4 a = *(const float4*)&zl[p][f4 * 4];
            float4 c = *(const float4*)&zr[p][f4 * 4];
            accl[p] += a.x * wl.x + a.y * wl.y + a.z * wl.z + a.w * wl.w;
            accr[p] += c.x * wr.x + c.y * wr.y + c.z * wr.z + c.w * wr.w;
        }
    }
    #pragma unroll
    for (int p = 0; p < NP; ++p) {
        int m = b * NN + i0 + p;
        hl_bf[m * HH + h] = f2b(celu1(accl[p]));
        hr_bf[m * HH + h] = f2b(celu1(accr[p]));
    }
}

// ---------------------------------------------------------------------------
// Kernel T: Wt[o][g][h] bf16  <-  bilinear_W[o][h][g] f32   (LDS transpose)
// grid: 8 blocks (one per o), 256 threads.
// ---------------------------------------------------------------------------
__global__ __launch_bounds__(256) void wt_kernel(
    const float* __restrict__ W, ushort* __restrict__ Wt)
{
    int o = blockIdx.x;
    int tid = threadIdx.x;
    __shared__ float lds[128 * 65];

    for (int h0 = 0; h0 < HH; h0 += 64) {
        for (int idx = tid; idx < 64 * 128; idx += 256) {
            int hh = idx >> 7;           // 0..63
            int g  = idx & 127;
            lds[g * 65 + hh] = W[(o * HH + h0 + hh) * HH + g];
        }
        __syncthreads();
        for (int idx = tid; idx < 128 * 64; idx += 256) {
            int g  = idx >> 6;           // 0..127
            int hh = idx & 63;
            Wt[(o * HH + g) * HH + h0 + hh] = f2b(lds[g * 65 + hh]);
        }
        __syncthreads();
    }
}

// ---------------------------------------------------------------------------
// Kernel B: t[m][o][g] = sum_h hl[m][h] * W[o][h][g], via MFMA with
// D[g][m] = Wt[o] (A, rows=g) x hl^T (B, cols=m).  All frags contiguous 16B.
// grid: dim3(16, 8) = (m-block of 64, o), 256 threads (4 waves, 16 m each).
// ---------------------------------------------------------------------------
__global__ __launch_bounds__(256) void t_kernel(
    const ushort* __restrict__ hl_bf, const ushort* __restrict__ Wt,
    ushort* __restrict__ t_bf)
{
    int o  = blockIdx.y;
    int m0 = blockIdx.x * 64;
    int tid  = threadIdx.x;
    int wave = tid >> 6;
    int lane = tid & 63;
    int lrow = lane & 15;
    int lgrp = lane >> 4;

    int m_wave = m0 + wave * 16;

    f32x4 acc[8];
    #pragma unroll
    for (int gt = 0; gt < 8; ++gt) acc[gt] = (f32x4)(0.0f);

    const ushort* Wo = Wt + o * HH * HH;

    #pragma unroll
    for (int kk = 0; kk < 4; ++kk) {
        int koff = kk * 32 + lgrp * 8;
        short8 a[8];
        #pragma unroll
        for (int gt = 0; gt < 8; ++gt)
            a[gt] = *(const short8*)&Wo[(gt * 16 + lrow) * HH + koff];
        short8 bfrag = *(const short8*)&hl_bf[(m_wave + lrow) * HH + koff];
        #pragma unroll
        for (int gt = 0; gt < 8; ++gt)
            acc[gt] = __builtin_amdgcn_mfma_f32_16x16x32_bf16(a[gt], bfrag, acc[gt], 0, 0, 0);
    }

    int m = m_wave + lrow;
    #pragma unroll
    for (int gt = 0; gt < 8; ++gt) {
        int g0 = gt * 16 + lgrp * 4;
        uint lo = (uint)f2b(acc[gt][0]) | ((uint)f2b(acc[gt][1]) << 16);
        uint hi = (uint)f2b(acc[gt][2]) | ((uint)f2b(acc[gt][3]) << 16);
        uint2 v; v.x = lo; v.y = hi;
        *(uint2*)&t_bf[(m * NOUT + o) * HH + g0] = v;
    }
}

// ---------------------------------------------------------------------------
// Kernel C: out[b,i,j,o] = sum_g t[b,(i,o)][g] * hr[b,j][g] + bias[o]
// GEMM per batch: M=4096 (=(i,o)), N=512 (=j), K=128.  MFMA 16x16x32.
// grid: dim3(N/128, M/64, B), 256 threads (4 waves; wave = 32 j, 64 m).
// ---------------------------------------------------------------------------
__global__ __launch_bounds__(256) void out_kernel(
    const ushort* __restrict__ t_bf, const ushort* __restrict__ hr_bf,
    const float* __restrict__ bias, float* __restrict__ out)
{
    int b  = blockIdx.z;
    int m0 = blockIdx.y * 64;              // within batch, multiple of 16
    int j0 = blockIdx.x * 128;
    int tid  = threadIdx.x;
    int wave = tid >> 6;
    int lane = tid & 63;
    int lrow = lane & 15;
    int lgrp = lane >> 4;

    int jw = j0 + wave * 32;

    f32x4 acc[4][2];
    #pragma unroll
    for (int mt = 0; mt < 4; ++mt)
        #pragma unroll
        for (int jt = 0; jt < 2; ++jt) acc[mt][jt] = (f32x4)(0.0f);

    const ushort* tb = t_bf + (size_t)b * (NN * NOUT) * HH;
    const ushort* hb = hr_bf + (size_t)b * NN * HH;

    #pragma unroll
    for (int kk = 0; kk < 4; ++kk) {
        int koff = kk * 32 + lgrp * 8;
        short8 a[4], bf[2];
        #pragma unroll
        for (int mt = 0; mt < 4; ++mt)
            a[mt] = *(const short8*)&tb[(m0 + mt * 16 + lrow) * HH + koff];
        #pragma unroll
        for (int jt = 0; jt < 2; ++jt)
            bf[jt] = *(const short8*)&hb[(jw + jt * 16 + lrow) * HH + koff];
        #pragma unroll
        for (int mt = 0; mt < 4; ++mt)
            #pragma unroll
            for (int jt = 0; jt < 2; ++jt)
                acc[mt][jt] = __builtin_amdgcn_mfma_f32_16x16x32_bf16(a[mt], bf[jt], acc[mt][jt], 0, 0, 0);
    }

    float4 b0 = *(const float4*)&bias[0];
    float4 b1 = *(const float4*)&bias[4];

    #pragma unroll
    for (int mt = 0; mt < 4; ++mt) {
        int m_base = m0 + mt * 16 + lgrp * 4;   // multiple of 4
        int i  = m_base >> 3;
        int o0 = m_base & 7;                    // 0 or 4
        float4 bv = o0 ? b1 : b0;
        #pragma unroll
        for (int jt = 0; jt < 2; ++jt) {
            int j = jw + jt * 16 + lrow;
            float4 v;
            v.x = acc[mt][jt][0] + bv.x;
            v.y = acc[mt][jt][1] + bv.y;
            v.z = acc[mt][jt][2] + bv.z;
            v.w = acc[mt][jt][3] + bv.w;
            float* dst = out + ((size_t)((b * NN + i) * NN + j)) * NOUT + o0;
            *(float4*)dst = v;
        }
    }
}

// ---------------------------------------------------------------------------
extern "C" void kernel_launch(void* const* d_in, const int* in_sizes, int n_in,
                              void* d_out, int out_size, void* d_ws, size_t ws_size,
                              hipStream_t stream) {
    const float* x_l  = (const float*)d_in[0];
    const float* x_r  = (const float*)d_in[1];
    const float* Wl   = (const float*)d_in[2];
    const float* bl   = (const float*)d_in[3];
    const float* Wr   = (const float*)d_in[4];
    const float* br   = (const float*)d_in[5];
    const float* Wb   = (const float*)d_in[6];
    const float* bb   = (const float*)d_in[7];
    float* out = (float*)d_out;

    ushort* hl_bf = (ushort*)d_ws;                       // B*N*H = 131072
    ushort* hr_bf = hl_bf + BB * NN * HH;                // 131072
    ushort* Wt    = hr_bf + BB * NN * HH;                // 8*128*128 = 131072
    ushort* t_bf  = Wt + NOUT * HH * HH;                 // B*N*8*H = 1048576

    h_kernel<<<BB * NN / 4, 128, 0, stream>>>(x_l, x_r, Wl, bl, Wr, br, hl_bf, hr_bf);
    wt_kernel<<<NOUT, 256, 0, stream>>>(Wb, Wt);
    t_kernel<<<dim3(16, NOUT), 256, 0, stream>>>(hl_bf, Wt, t_bf);
    out_kernel<<<dim3(NN / 128, 4096 / 64, BB), 256, 0, stream>>>(t_bf, hr_bf, bb, out);
}

// Round 3
// 30.584 us; speedup vs baseline: 1.9431x; 1.4463x over previous
//
#include <hip/hip_runtime.h>
#include <math.h>

#define BB 2
#define NN 512
#define NIN 64
#define NF 192
#define HH 128
#define NOUT 8

typedef short short8 __attribute__((ext_vector_type(8)));
typedef float f32x4 __attribute__((ext_vector_type(4)));

__device__ __forceinline__ float celu1(float x) {
    return x > 0.0f ? x : expm1f(x);
}

__device__ __forceinline__ ushort f2b(float f) {
    union { float f; uint u; } v; v.f = f;
    uint r = v.u + 0x7fffu + ((v.u >> 16) & 1u);   // RNE
    return (ushort)(r >> 16);
}
__device__ __forceinline__ uint pack2(float a, float b) {
    return (uint)f2b(a) | ((uint)f2b(b) << 16);
}

// ---------------------------------------------------------------------------
// prep: bf16-ize x_l, x_r, Wl, Wr; transpose+cvt bilinear_W -> Wt[o][g][h].
// grid 84 blocks x 256:
//   [0,32)  x_l cvt   (2048 elems/blk)
//   [32,64) x_r cvt
//   [64,70) Wl cvt    (4096 elems/blk)
//   [70,76) Wr cvt
//   [76,84) Wt transpose, o = blk-76
// ---------------------------------------------------------------------------
__global__ __launch_bounds__(256) void prep_kernel(
    const float* __restrict__ x_l, const float* __restrict__ x_r,
    const float* __restrict__ Wl, const float* __restrict__ Wr,
    const float* __restrict__ Wb,
    ushort* __restrict__ xl_bf, ushort* __restrict__ xr_bf,
    ushort* __restrict__ Wl_bf, ushort* __restrict__ Wr_bf,
    ushort* __restrict__ Wt)
{
    int blk = blockIdx.x;
    int tid = threadIdx.x;

    if (blk < 64) {
        const float* src = (blk < 32) ? x_l : x_r;
        ushort* dst = (blk < 32) ? xl_bf : xr_bf;
        int off = (blk & 31) * 2048 + tid * 8;
        float4 v0 = *(const float4*)&src[off];
        float4 v1 = *(const float4*)&src[off + 4];
        uint4 p;
        p.x = pack2(v0.x, v0.y); p.y = pack2(v0.z, v0.w);
        p.z = pack2(v1.x, v1.y); p.w = pack2(v1.z, v1.w);
        *(uint4*)&dst[off] = p;
    } else if (blk < 76) {
        const float* src = (blk < 70) ? Wl : Wr;
        ushort* dst = (blk < 70) ? Wl_bf : Wr_bf;
        int off = ((blk < 70) ? (blk - 64) : (blk - 70)) * 4096 + tid * 16;
        uint4 p0, p1;
        {
            float4 a = *(const float4*)&src[off];
            float4 b = *(const float4*)&src[off + 4];
            p0.x = pack2(a.x, a.y); p0.y = pack2(a.z, a.w);
            p0.z = pack2(b.x, b.y); p0.w = pack2(b.z, b.w);
        }
        {
            float4 a = *(const float4*)&src[off + 8];
            float4 b = *(const float4*)&src[off + 12];
            p1.x = pack2(a.x, a.y); p1.y = pack2(a.z, a.w);
            p1.z = pack2(b.x, b.y); p1.w = pack2(b.z, b.w);
        }
        *(uint4*)&dst[off] = p0;
        *(uint4*)&dst[off + 8] = p1;
    } else {
        int o = blk - 76;
        __shared__ float lds[128 * 65];
        for (int h0 = 0; h0 < HH; h0 += 64) {
            for (int idx = tid; idx < 64 * 128; idx += 256) {
                int hh = idx >> 7;           // 0..63
                int g  = idx & 127;
                lds[g * 65 + hh] = Wb[(o * HH + h0 + hh) * HH + g];
            }
            __syncthreads();
            for (int idx = tid; idx < 128 * 64; idx += 256) {
                int g  = idx >> 6;           // 0..127
                int hh = idx & 63;
                Wt[(o * HH + g) * HH + h0 + hh] = f2b(lds[g * 65 + hh]);
            }
            __syncthreads();
        }
    }
}

// ---------------------------------------------------------------------------
// H: hl[m][h] = celu(sum_f zl[m][f] Wl[h][f] + bl[h]) (and hr), via MFMA.
// Pairing folded into the B-fragment load: part = kk>>1 (uniform per step),
//   zl parts: {x_l, x_l[i-1], x_l[i+1]}, zr parts: {x_l (faithful bug),
//   x_r[i+1], x_r[i-1]}; out-of-range rows -> zero fragment.
// grid dim3(64, 4): blk.x = m-tile of 16, blk.y = h-quarter (32 h).
// 4 waves: wave = (hsub, lr); each wave one 16x16 MFMA tile, K=192.
// ---------------------------------------------------------------------------
__global__ __launch_bounds__(256) void h_kernel(
    const ushort* __restrict__ xl_bf, const ushort* __restrict__ xr_bf,
    const ushort* __restrict__ Wl_bf, const ushort* __restrict__ Wr_bf,
    const float* __restrict__ bl, const float* __restrict__ br,
    ushort* __restrict__ hl_bf, ushort* __restrict__ hr_bf)
{
    int m0 = blockIdx.x * 16;
    int b  = m0 >> 9;
    int i  = (m0 & (NN - 1)) + (threadIdx.x & 15);
    int tid  = threadIdx.x;
    int wave = tid >> 6;
    int lane = tid & 63;
    int lrow = lane & 15;
    int lgrp = lane >> 4;
    int lr   = wave & 1;
    int h0   = blockIdx.y * 32 + (wave >> 1) * 16;

    const ushort* Wm   = lr ? Wr_bf : Wl_bf;
    const ushort* xalt = lr ? xr_bf : xl_bf;
    const float*  bias = lr ? br : bl;
    ushort* dst        = lr ? hr_bf : hl_bf;

    f32x4 acc = (f32x4)(0.0f);

    #pragma unroll
    for (int kk = 0; kk < 6; ++kk) {
        int f0 = kk * 32 + lgrp * 8;
        int part = kk >> 1;                  // uniform over lanes
        int c0 = f0 & 63;
        int s; const ushort* src;
        if (part == 0)      { s = 0;            src = xl_bf; }
        else if (part == 1) { s = lr ? +1 : -1; src = xalt; }
        else                { s = lr ? -1 : +1; src = xalt; }
        int row = i + s;
        short8 bfrag = (short8)0;
        if ((unsigned)row < (unsigned)NN)
            bfrag = *(const short8*)&src[(b * NN + row) * NIN + c0];
        short8 afrag = *(const short8*)&Wm[(h0 + lrow) * NF + f0];
        acc = __builtin_amdgcn_mfma_f32_16x16x32_bf16(afrag, bfrag, acc, 0, 0, 0);
    }

    int h_base = h0 + lgrp * 4;
    float4 bv = *(const float4*)&bias[h_base];
    int m = m0 + lrow;
    uint2 v;
    v.x = pack2(celu1(acc[0] + bv.x), celu1(acc[1] + bv.y));
    v.y = pack2(celu1(acc[2] + bv.z), celu1(acc[3] + bv.w));
    *(uint2*)&dst[m * HH + h_base] = v;
}

// ---------------------------------------------------------------------------
// t: t[m][o][g] = sum_h hl[m][h] * Wt[o][g][h], MFMA, D[g][m].
// grid dim3(64, 8): blk.x = m-tile of 16, blk.y = o. wave w -> g range w*32.
// ---------------------------------------------------------------------------
__global__ __launch_bounds__(256) void t_kernel(
    const ushort* __restrict__ hl_bf, const ushort* __restrict__ Wt,
    ushort* __restrict__ t_bf)
{
    int o  = blockIdx.y;
    int m0 = blockIdx.x * 16;
    int tid  = threadIdx.x;
    int wave = tid >> 6;
    int lane = tid & 63;
    int lrow = lane & 15;
    int lgrp = lane >> 4;
    int g_base = wave * 32;

    f32x4 acc[2];
    acc[0] = (f32x4)(0.0f);
    acc[1] = (f32x4)(0.0f);

    const ushort* Wo = Wt + o * HH * HH;

    #pragma unroll
    for (int kk = 0; kk < 4; ++kk) {
        int koff = kk * 32 + lgrp * 8;
        short8 bfrag = *(const short8*)&hl_bf[(m0 + lrow) * HH + koff];
        short8 a0 = *(const short8*)&Wo[(g_base + lrow) * HH + koff];
        short8 a1 = *(const short8*)&Wo[(g_base + 16 + lrow) * HH + koff];
        acc[0] = __builtin_amdgcn_mfma_f32_16x16x32_bf16(a0, bfrag, acc[0], 0, 0, 0);
        acc[1] = __builtin_amdgcn_mfma_f32_16x16x32_bf16(a1, bfrag, acc[1], 0, 0, 0);
    }

    int m = m0 + lrow;
    #pragma unroll
    for (int gt = 0; gt < 2; ++gt) {
        int g0 = g_base + gt * 16 + lgrp * 4;
        uint2 v;
        v.x = pack2(acc[gt][0], acc[gt][1]);
        v.y = pack2(acc[gt][2], acc[gt][3]);
        *(uint2*)&t_bf[(m * NOUT + o) * HH + g0] = v;
    }
}

// ---------------------------------------------------------------------------
// out: out[b,i,j,o] = sum_g t[b,(i,o)][g] * hr[b,j][g] + bias[o]
// GEMM per batch: M=4096 (=(i,o)), N=512 (=j), K=128.  MFMA 16x16x32.
// grid: dim3(N/128, M/64, B), 256 threads (4 waves; wave = 32 j, 64 m).
// ---------------------------------------------------------------------------
__global__ __launch_bounds__(256) void out_kernel(
    const ushort* __restrict__ t_bf, const ushort* __restrict__ hr_bf,
    const float* __restrict__ bias, float* __restrict__ out)
{
    int b  = blockIdx.z;
    int m0 = blockIdx.y * 64;
    int j0 = blockIdx.x * 128;
    int tid  = threadIdx.x;
    int wave = tid >> 6;
    int lane = tid & 63;
    int lrow = lane & 15;
    int lgrp = lane >> 4;

    int jw = j0 + wave * 32;

    f32x4 acc[4][2];
    #pragma unroll
    for (int mt = 0; mt < 4; ++mt)
        #pragma unroll
        for (int jt = 0; jt < 2; ++jt) acc[mt][jt] = (f32x4)(0.0f);

    const ushort* tb = t_bf + (size_t)b * (NN * NOUT) * HH;
    const ushort* hb = hr_bf + (size_t)b * NN * HH;

    #pragma unroll
    for (int kk = 0; kk < 4; ++kk) {
        int koff = kk * 32 + lgrp * 8;
        short8 a[4], bf[2];
        #pragma unroll
        for (int mt = 0; mt < 4; ++mt)
            a[mt] = *(const short8*)&tb[(m0 + mt * 16 + lrow) * HH + koff];
        #pragma unroll
        for (int jt = 0; jt < 2; ++jt)
            bf[jt] = *(const short8*)&hb[(jw + jt * 16 + lrow) * HH + koff];
        #pragma unroll
        for (int mt = 0; mt < 4; ++mt)
            #pragma unroll
            for (int jt = 0; jt < 2; ++jt)
                acc[mt][jt] = __builtin_amdgcn_mfma_f32_16x16x32_bf16(a[mt], bf[jt], acc[mt][jt], 0, 0, 0);
    }

    float4 b0 = *(const float4*)&bias[0];
    float4 b1 = *(const float4*)&bias[4];

    #pragma unroll
    for (int mt = 0; mt < 4; ++mt) {
        int m_base = m0 + mt * 16 + lgrp * 4;   // multiple of 4
        int i  = m_base >> 3;
        int o0 = m_base & 7;                    // 0 or 4
        float4 bv = o0 ? b1 : b0;
        #pragma unroll
        for (int jt = 0; jt < 2; ++jt) {
            int j = jw + jt * 16 + lrow;
            float4 v;
            v.x = acc[mt][jt][0] + bv.x;
            v.y = acc[mt][jt][1] + bv.y;
            v.z = acc[mt][jt][2] + bv.z;
            v.w = acc[mt][jt][3] + bv.w;
            float* dst = out + ((size_t)((b * NN + i) * NN + j)) * NOUT + o0;
            *(float4*)dst = v;
        }
    }
}

// ---------------------------------------------------------------------------
extern "C" void kernel_launch(void* const* d_in, const int* in_sizes, int n_in,
                              void* d_out, int out_size, void* d_ws, size_t ws_size,
                              hipStream_t stream) {
    const float* x_l  = (const float*)d_in[0];
    const float* x_r  = (const float*)d_in[1];
    const float* Wl   = (const float*)d_in[2];
    const float* bl   = (const float*)d_in[3];
    const float* Wr   = (const float*)d_in[4];
    const float* br   = (const float*)d_in[5];
    const float* Wb   = (const float*)d_in[6];
    const float* bb   = (const float*)d_in[7];
    float* out = (float*)d_out;

    ushort* xl_bf = (ushort*)d_ws;                   // 65536
    ushort* xr_bf = xl_bf + BB * NN * NIN;           // 65536
    ushort* Wl_bf = xr_bf + BB * NN * NIN;           // 24576
    ushort* Wr_bf = Wl_bf + HH * NF;                 // 24576
    ushort* Wt    = Wr_bf + HH * NF;                 // 131072
    ushort* hl_bf = Wt + NOUT * HH * HH;             // 131072
    ushort* hr_bf = hl_bf + BB * NN * HH;            // 131072
    ushort* t_bf  = hr_bf + BB * NN * HH;            // 1048576

    prep_kernel<<<84, 256, 0, stream>>>(x_l, x_r, Wl, Wr, Wb,
                                        xl_bf, xr_bf, Wl_bf, Wr_bf, Wt);
    h_kernel<<<dim3(BB * NN / 16, 4), 256, 0, stream>>>(
        xl_bf, xr_bf, Wl_bf, Wr_bf, bl, br, hl_bf, hr_bf);
    t_kernel<<<dim3(BB * NN / 16, NOUT), 256, 0, stream>>>(hl_bf, Wt, t_bf);
    out_kernel<<<dim3(NN / 128, 4096 / 64, BB), 256, 0, stream>>>(t_bf, hr_bf, bb, out);
}

// Round 4
// 26.716 us; speedup vs baseline: 2.2245x; 1.1448x over previous
//
#include <hip/hip_runtime.h>
#include <math.h>

#define BB 2
#define NN 512
#define NIN 64
#define NF 192
#define HH 128
#define NOUT 8

typedef short short8 __attribute__((ext_vector_type(8)));
typedef float f32x4 __attribute__((ext_vector_type(4)));

__device__ __forceinline__ float celu1(float x) {
    return x > 0.0f ? x : expm1f(x);
}

__device__ __forceinline__ ushort f2b(float f) {
    union { float f; uint u; } v; v.f = f;
    uint r = v.u + 0x7fffu + ((v.u >> 16) & 1u);   // RNE
    return (ushort)(r >> 16);
}
__device__ __forceinline__ uint pack2(float a, float b) {
    return (uint)f2b(a) | ((uint)f2b(b) << 16);
}
// load 8 consecutive f32, convert to a bf16 MFMA fragment in-register
__device__ __forceinline__ short8 cvt8(const float* __restrict__ p) {
    float4 a = *(const float4*)p;
    float4 b = *(const float4*)(p + 4);
    union { uint4 u; short8 s; } c;
    c.u.x = pack2(a.x, a.y); c.u.y = pack2(a.z, a.w);
    c.u.z = pack2(b.x, b.y); c.u.w = pack2(b.z, b.w);
    return c.s;
}

// ---------------------------------------------------------------------------
// K1: blocks [0,256): fc layer via MFMA, reading f32 x/W with in-register cvt.
//     blk = mb | (lr<<6) | (hh<<7): m-tile 16, l/r select, h-half (64 h).
//     wave w -> h-tile h0 = hh*64 + w*16.  K=192 (6 MFMA steps), pairing
//     folded into B-frag addressing (part = kk>>1, uniform).
//     blocks [256,264): transpose+cvt bilinear_W[o][h][g] -> Wt[o][g][h].
// ---------------------------------------------------------------------------
__global__ __launch_bounds__(256) void k1_kernel(
    const float* __restrict__ x_l, const float* __restrict__ x_r,
    const float* __restrict__ Wl, const float* __restrict__ bl,
    const float* __restrict__ Wr, const float* __restrict__ br,
    const float* __restrict__ Wb,
    ushort* __restrict__ hl_bf, ushort* __restrict__ hr_bf,
    ushort* __restrict__ Wt)
{
    __shared__ float lds[128 * 65];   // used only by transpose blocks
    int blk = blockIdx.x;
    int tid = threadIdx.x;

    if (blk < 256) {
        int mb = blk & 63;
        int lr = (blk >> 6) & 1;
        int hh = blk >> 7;
        int m0 = mb * 16;
        int b  = m0 >> 9;
        int i_base = m0 & (NN - 1);

        int wave = tid >> 6;
        int lane = tid & 63;
        int lrow = lane & 15;
        int lgrp = lane >> 4;
        int h0 = hh * 64 + wave * 16;
        int i = i_base + lrow;

        const float* Wm   = lr ? Wr : Wl;
        const float* bias = lr ? br : bl;
        const float* xa   = lr ? x_r : x_l;
        ushort* dst       = lr ? hr_bf : hl_bf;

        // B-fragments (shared over h-tiles): pairing folded into address
        short8 bf[6];
        #pragma unroll
        for (int kk = 0; kk < 6; ++kk) {
            int part = kk >> 1;
            int c0 = (kk & 1) * 32 + lgrp * 8;
            int s; const float* src;
            if (part == 0)      { s = 0;            src = x_l; }
            else if (part == 1) { s = lr ? +1 : -1; src = xa; }
            else                { s = lr ? -1 : +1; src = xa; }
            int row = i + s;
            short8 v = (short8)0;
            if ((unsigned)row < (unsigned)NN)
                v = cvt8(&src[(b * NN + row) * NIN + c0]);
            bf[kk] = v;
        }

        f32x4 acc = (f32x4)(0.0f);
        #pragma unroll
        for (int kk = 0; kk < 6; ++kk) {
            short8 afrag = cvt8(&Wm[(h0 + lrow) * NF + kk * 32 + lgrp * 8]);
            acc = __builtin_amdgcn_mfma_f32_16x16x32_bf16(afrag, bf[kk], acc, 0, 0, 0);
        }

        int h_base = h0 + lgrp * 4;
        float4 bv = *(const float4*)&bias[h_base];
        int m = m0 + lrow;
        uint2 v;
        v.x = pack2(celu1(acc[0] + bv.x), celu1(acc[1] + bv.y));
        v.y = pack2(celu1(acc[2] + bv.z), celu1(acc[3] + bv.w));
        *(uint2*)&dst[m * HH + h_base] = v;
    } else {
        int o = blk - 256;
        for (int h0 = 0; h0 < HH; h0 += 64) {
            for (int idx = tid; idx < 64 * 128; idx += 256) {
                int hh = idx >> 7;           // 0..63
                int g  = idx & 127;
                lds[g * 65 + hh] = Wb[(o * HH + h0 + hh) * HH + g];
            }
            __syncthreads();
            for (int idx = tid; idx < 128 * 64; idx += 256) {
                int g  = idx >> 6;           // 0..127
                int hh = idx & 63;
                Wt[(o * HH + g) * HH + h0 + hh] = f2b(lds[g * 65 + hh]);
            }
            __syncthreads();
        }
    }
}

// ---------------------------------------------------------------------------
// K2: fused t + out.  grid dim3(4, 32, 2), 256 threads (4 waves).
// Phase 1: t-tile[m=128 local][g=128] in LDS via MFMA D[g][i]:
//   A = Wt[o][g][h] (rows=g, contiguous h), B = hl[i0+i][h] (cols=i).
//   wave w covers g in [w*32, w*32+32), all 8 o.
// Phase 2: out[i0+di, j0+dj, o] = sum_g t_s[m][g] * hr[j][g] + bias[o].
//   Standard 16x16x32 GEMM, A-frags from LDS (row stride 136 ushorts = 272 B,
//   16B-aligned, read-conflict-free), B from global hr.
// ---------------------------------------------------------------------------
#define TSTR 136   // t_s row stride in ushorts (128 + 8)

__global__ __launch_bounds__(256) void k2_kernel(
    const ushort* __restrict__ hl_bf, const ushort* __restrict__ hr_bf,
    const ushort* __restrict__ Wt, const float* __restrict__ bias,
    float* __restrict__ out)
{
    __shared__ ushort t_s[128 * TSTR];   // 34816 B

    int j0 = blockIdx.x * 128;
    int i0 = blockIdx.y * 16;
    int b  = blockIdx.z;
    int tid  = threadIdx.x;
    int wave = tid >> 6;
    int lane = tid & 63;
    int lrow = lane & 15;
    int lgrp = lane >> 4;

    // ---- phase 1: build t tile in LDS ----
    short8 hfrag[4];
    #pragma unroll
    for (int kk = 0; kk < 4; ++kk)
        hfrag[kk] = *(const short8*)&hl_bf[(b * NN + i0 + lrow) * HH + kk * 32 + lgrp * 8];

    #pragma unroll
    for (int o = 0; o < NOUT; ++o) {
        #pragma unroll
        for (int gt = 0; gt < 2; ++gt) {
            int g_base = wave * 32 + gt * 16;
            f32x4 acc = (f32x4)(0.0f);
            #pragma unroll
            for (int kk = 0; kk < 4; ++kk) {
                short8 afrag = *(const short8*)&Wt[(o * HH + g_base + lrow) * HH + kk * 32 + lgrp * 8];
                acc = __builtin_amdgcn_mfma_f32_16x16x32_bf16(afrag, hfrag[kk], acc, 0, 0, 0);
            }
            // lane holds: i = lrow (col), g = g_base + lgrp*4 + r (row)
            int m  = lrow * 8 + o;           // local m = (i_loc, o)
            int gg = g_base + lgrp * 4;
            uint2 v;
            v.x = pack2(acc[0], acc[1]);
            v.y = pack2(acc[2], acc[3]);
            *(uint2*)&t_s[m * TSTR + gg] = v;
        }
    }
    __syncthreads();

    // ---- phase 2: main GEMM, A from LDS ----
    int jw = j0 + wave * 32;

    f32x4 acc2[8][2];
    #pragma unroll
    for (int ms = 0; ms < 8; ++ms)
        #pragma unroll
        for (int jt = 0; jt < 2; ++jt) acc2[ms][jt] = (f32x4)(0.0f);

    const ushort* hb = hr_bf + (size_t)b * NN * HH;

    #pragma unroll
    for (int kk = 0; kk < 4; ++kk) {
        int koff = kk * 32 + lgrp * 8;
        short8 bfr[2];
        #pragma unroll
        for (int jt = 0; jt < 2; ++jt)
            bfr[jt] = *(const short8*)&hb[(jw + jt * 16 + lrow) * HH + koff];
        #pragma unroll
        for (int ms = 0; ms < 8; ++ms) {
            short8 afr = *(const short8*)&t_s[(ms * 16 + lrow) * TSTR + koff];
            #pragma unroll
            for (int jt = 0; jt < 2; ++jt)
                acc2[ms][jt] = __builtin_amdgcn_mfma_f32_16x16x32_bf16(afr, bfr[jt], acc2[ms][jt], 0, 0, 0);
        }
    }

    float4 b0 = *(const float4*)&bias[0];
    float4 b1 = *(const float4*)&bias[4];

    #pragma unroll
    for (int ms = 0; ms < 8; ++ms) {
        int m_base = ms * 16 + lgrp * 4;       // local m, multiple of 4
        int i  = i0 + (m_base >> 3);
        int o0 = m_base & 7;                   // 0 or 4
        float4 bv = o0 ? b1 : b0;
        #pragma unroll
        for (int jt = 0; jt < 2; ++jt) {
            int j = jw + jt * 16 + lrow;
            float4 v;
            v.x = acc2[ms][jt][0] + bv.x;
            v.y = acc2[ms][jt][1] + bv.y;
            v.z = acc2[ms][jt][2] + bv.z;
            v.w = acc2[ms][jt][3] + bv.w;
            float* dst = out + ((size_t)((b * NN + i) * NN + j)) * NOUT + o0;
            *(float4*)dst = v;
        }
    }
}

// ---------------------------------------------------------------------------
extern "C" void kernel_launch(void* const* d_in, const int* in_sizes, int n_in,
                              void* d_out, int out_size, void* d_ws, size_t ws_size,
                              hipStream_t stream) {
    const float* x_l  = (const float*)d_in[0];
    const float* x_r  = (const float*)d_in[1];
    const float* Wl   = (const float*)d_in[2];
    const float* bl   = (const float*)d_in[3];
    const float* Wr   = (const float*)d_in[4];
    const float* br   = (const float*)d_in[5];
    const float* Wb   = (const float*)d_in[6];
    const float* bb   = (const float*)d_in[7];
    float* out = (float*)d_out;

    ushort* hl_bf = (ushort*)d_ws;                   // B*N*H = 131072
    ushort* hr_bf = hl_bf + BB * NN * HH;            // 131072
    ushort* Wt    = hr_bf + BB * NN * HH;            // 8*128*128 = 131072

    k1_kernel<<<264, 256, 0, stream>>>(x_l, x_r, Wl, bl, Wr, br, Wb,
                                       hl_bf, hr_bf, Wt);
    k2_kernel<<<dim3(NN / 128, NN / 16, BB), 256, 0, stream>>>(
        hl_bf, hr_bf, Wt, bb, out);
}